// Round 1
// baseline (106.923 us; speedup 1.0000x reference)
//
#include <hip/hip_runtime.h>
#include <hip/hip_bf16.h>
#include <math.h>

// RingConv2d fused:
//   out[b,o,h,w] = atan2( sum_p sin(x_p - w_p), sum_p cos(x_p - w_p) )
// ringify is a no-op under sin/cos (2*pi periodic). Expand:
//   cos(x-w) = cos x cos w + sin x sin w
//   sin(x-w) = sin x cos w - cos x sin w
// => four standard 3x3 convs on (cos x, sin x) planes + atan2 epilogue.
// Zero-padding of x maps to (cos=1, sin=0), handled by sincos of a 0 halo.

#define B_   4
#define C_   32
#define H_   64
#define W_   64
#define O_   64
#define K_   3
#define TH   16
#define TW   16
#define OC   8    // output channels per block
#define CG   8    // input channels per LDS group

// ---- weight transform: w[O][C][3][3] -> wt[C*9][O][2] (cos, sin interleaved)
__global__ __launch_bounds__(256) void ring_wtrans(const float* __restrict__ w,
                                                   float* __restrict__ wt) {
    int idx = blockIdx.x * 256 + threadIdx.x;   // 0 .. O*C*9-1
    if (idx >= O_ * C_ * K_ * K_) return;
    int o = idx / (C_ * K_ * K_);
    int r = idx % (C_ * K_ * K_);               // r = c*9 + i*3 + j
    float v = w[idx];
    float s, c;
    __sincosf(v, &s, &c);
    wt[(r * O_ + o) * 2 + 0] = c;
    wt[(r * O_ + o) * 2 + 1] = s;
}

// ---- main conv kernel
__global__ __launch_bounds__(256) void ring_conv(const float* __restrict__ x,
                                                 const float* __restrict__ wt,
                                                 float* __restrict__ out) {
    // grid: (16 tiles, O/OC, B)
    __shared__ float cx_s[CG][18][18];
    __shared__ float sx_s[CG][18][18];

    const int tid = threadIdx.x;
    const int tile   = blockIdx.x;              // 0..15
    const int tile_y = (tile / (W_ / TW)) * TH;
    const int tile_x = (tile % (W_ / TW)) * TW;
    const int ob = blockIdx.y * OC;             // first output channel
    const int b  = blockIdx.z;

    const int ty = tid >> 4;                    // 0..15
    const int tx = tid & 15;                    // 0..15

    float ax[OC], ay[OC];
#pragma unroll
    for (int o = 0; o < OC; ++o) { ax[o] = 0.f; ay[o] = 0.f; }

    const float* xb = x + (size_t)b * C_ * H_ * W_;

    for (int cg = 0; cg < C_; cg += CG) {
        __syncthreads();
        // stage CG x 18 x 18 sin/cos values (zero halo outside the image)
        for (int i = tid; i < CG * 18 * 18; i += 256) {
            int c  = i / 324;
            int rr = i % 324;
            int r  = rr / 18;
            int cl = rr % 18;
            int hh = tile_y + r - 1;
            int ww = tile_x + cl - 1;
            float v = 0.f;
            if (hh >= 0 && hh < H_ && ww >= 0 && ww < W_)
                v = xb[(cg + c) * (H_ * W_) + hh * W_ + ww];
            float s, cc;
            __sincosf(v, &s, &cc);
            cx_s[c][r][cl] = cc;
            sx_s[c][r][cl] = s;
        }
        __syncthreads();

#pragma unroll 1
        for (int c = 0; c < CG; ++c) {
            const float* wrow = wt + ((size_t)(cg + c) * 9 * O_ + ob) * 2;
#pragma unroll
            for (int i = 0; i < K_; ++i) {
#pragma unroll
                for (int j = 0; j < K_; ++j) {
                    float cxv = cx_s[c][ty + i][tx + j];
                    float sxv = sx_s[c][ty + i][tx + j];
                    // uniform (block-wide) index -> scalar loads
                    const float* wp = wrow + (i * 3 + j) * O_ * 2;
#pragma unroll
                    for (int o = 0; o < OC; ++o) {
                        float cw = wp[2 * o + 0];
                        float sw = wp[2 * o + 1];
                        ax[o] = fmaf(cxv, cw, fmaf(sxv, sw, ax[o]));
                        ay[o] = fmaf(sxv, cw, fmaf(-cxv, sw, ay[o]));
                    }
                }
            }
        }
    }

    // epilogue: atan2 + store
    const int h = tile_y + ty;
    const int w2 = tile_x + tx;
    float* op = out + ((size_t)(b * O_ + ob) * (H_ * W_)) + h * W_ + w2;
#pragma unroll
    for (int o = 0; o < OC; ++o) {
        op[(size_t)o * (H_ * W_)] = atan2f(ay[o], ax[o]);
    }
}

extern "C" void kernel_launch(void* const* d_in, const int* in_sizes, int n_in,
                              void* d_out, int out_size, void* d_ws, size_t ws_size,
                              hipStream_t stream) {
    const float* x = (const float*)d_in[0];   // (4,32,64,64) f32
    const float* w = (const float*)d_in[1];   // (64,32,3,3)  f32
    float* out = (float*)d_out;               // (4,64,64,64) f32
    float* wt  = (float*)d_ws;                // C*9*O*2 floats = 147 KB

    ring_wtrans<<<dim3((O_ * C_ * K_ * K_ + 255) / 256), dim3(256), 0, stream>>>(w, wt);

    dim3 grid((H_ / TH) * (W_ / TW), O_ / OC, B_);
    ring_conv<<<grid, dim3(256), 0, stream>>>(x, wt, out);
}

// Round 2
// 104.627 us; speedup vs baseline: 1.0220x; 1.0220x over previous
//
#include <hip/hip_runtime.h>
#include <math.h>

// RingConv2d = atan2( sum sin(x-w), sum cos(x-w) ) over 3x3xC patches.
// cos(x-w) = cx*cw + sx*sw ; sin(x-w) = sx*cw - cx*sw  (ringify is a no-op).
// Packed-FMA formulation with two accumulators per output channel:
//   A = [ax1, ay1] += [cx,sx] * [cw,  cw]
//   B = [ay2, ax2] += [cx,sx] * [-sw, sw]
//   ax = A.x + B.y ; ay = A.y + B.x
// -> 2x v_pk_fma_f32 per (o,c,ij), weights as block-uniform SGPR pairs.

typedef float f32x2 __attribute__((ext_vector_type(2)));
typedef float f32x4 __attribute__((ext_vector_type(4)));

#define B_   4
#define C_   32
#define H_   64
#define W_   64
#define O_   64
#define OC   4          // output channels per block
#define CG   8          // input channels per LDS stage

#define WT_ENTRIES (O_ * C_ * 9)            // 18432 float4 entries
#define WT_BYTES   (WT_ENTRIES * 16)        // 294912 B (16B aligned)
#define NPIX       (B_ * C_ * H_ * W_)      // 524288 pixels

// ---- prep: weight trig table + input sincos planes, fused in one kernel
__global__ __launch_bounds__(256) void ring_prep(const float* __restrict__ x,
                                                 const float* __restrict__ w,
                                                 f32x4* __restrict__ wt,
                                                 f32x4* __restrict__ planes4) {
    const int bid = blockIdx.x;
    const int tid = threadIdx.x;
    if (bid < 72) {
        // 72*256 == 18432 == O*C*9 exactly. idx = ((o*C)+c)*9 + ki*3+kj
        int idx = bid * 256 + tid;
        int o = idx / (C_ * 9);
        int r = idx % (C_ * 9);             // r = c*9 + ki*3 + kj (patch order)
        float v = w[idx];
        float s, c;
        __sincosf(v, &s, &c);
        wt[r * O_ + o] = (f32x4){c, c, -s, s};
    } else {
        // two pixels per thread: (72+1024) blocks total, 1024*256*2 = NPIX
        int i = (bid - 72) * 256 + tid;     // float2-of-x index
        f32x2 xv = ((const f32x2*)x)[i];
        float s0, c0, s1, c1;
        __sincosf(xv.x, &s0, &c0);
        __sincosf(xv.y, &s1, &c1);
        planes4[i] = (f32x4){c0, s0, c1, s1};
    }
}

// ---- main conv
__global__ __launch_bounds__(256, 4) void ring_conv(const f32x2* __restrict__ cs,
                                                    const f32x4* __restrict__ wt,
                                                    float* __restrict__ out) {
    __shared__ f32x2 sm[CG][18][18];        // 20736 B

    const int tid = threadIdx.x;
    const int tile = blockIdx.x;            // 16 tiles of 16x16
    const int tile_y = (tile >> 2) * 16;
    const int tile_x = (tile & 3) * 16;
    const int ob = blockIdx.y * OC;         // 16 o-groups
    const int b  = blockIdx.z;

    const int ty = tid >> 4;
    const int tx = tid & 15;

    f32x2 accA[OC], accB[OC];
#pragma unroll
    for (int o = 0; o < OC; ++o) {
        accA[o] = (f32x2){0.f, 0.f};
        accB[o] = (f32x2){0.f, 0.f};
    }

    const f32x2* csb = cs + (size_t)b * C_ * (H_ * W_);

    for (int cg = 0; cg < C_; cg += CG) {
        __syncthreads();
        // stage CG x 18 x 18 (cos,sin) pairs; halo -> (1,0)
#pragma unroll 1
        for (int i = tid; i < CG * 18 * 18; i += 256) {
            int c  = i / 324;
            int rr = i % 324;
            int r  = rr / 18;
            int cl = rr % 18;
            int hh = tile_y + r - 1;
            int ww = tile_x + cl - 1;
            f32x2 v = (f32x2){1.f, 0.f};
            if ((unsigned)hh < (unsigned)H_ && (unsigned)ww < (unsigned)W_)
                v = csb[(cg + c) * (H_ * W_) + hh * W_ + ww];
            sm[c][r][cl] = v;
        }
        __syncthreads();

#pragma unroll 1
        for (int c = 0; c < CG; ++c) {
            // P fragments for the 9 taps (ds_read_b64 with imm offsets)
            f32x2 P[9];
#pragma unroll
            for (int i = 0; i < 3; ++i)
#pragma unroll
                for (int j = 0; j < 3; ++j)
                    P[i * 3 + j] = sm[c][ty + i][tx + j];

            const f32x4* wp = wt + (size_t)((cg + c) * 9) * O_ + ob;
#pragma unroll
            for (int ij = 0; ij < 9; ++ij) {
#pragma unroll
                for (int o = 0; o < OC; ++o) {
                    f32x4 e = wp[ij * O_ + o];      // uniform -> SGPR
                    f32x2 w1 = (f32x2){e.x, e.y};   // [cw, cw]
                    f32x2 w2 = (f32x2){e.z, e.w};   // [-sw, sw]
                    asm("v_pk_fma_f32 %0, %1, %2, %0"
                        : "+v"(accA[o]) : "v"(P[ij]), "s"(w1));
                    asm("v_pk_fma_f32 %0, %1, %2, %0"
                        : "+v"(accB[o]) : "v"(P[ij]), "s"(w2));
                }
            }
        }
    }

    const int h = tile_y + ty;
    const int wcol = tile_x + tx;
    float* op = out + (size_t)(b * O_ + ob) * (H_ * W_) + h * W_ + wcol;
#pragma unroll
    for (int o = 0; o < OC; ++o) {
        float ax = accA[o].x + accB[o].y;
        float ay = accA[o].y + accB[o].x;
        op[(size_t)o * (H_ * W_)] = atan2f(ay, ax);
    }
}

extern "C" void kernel_launch(void* const* d_in, const int* in_sizes, int n_in,
                              void* d_out, int out_size, void* d_ws, size_t ws_size,
                              hipStream_t stream) {
    const float* x = (const float*)d_in[0];   // (4,32,64,64) f32
    const float* w = (const float*)d_in[1];   // (64,32,3,3)  f32
    float* out = (float*)d_out;               // (4,64,64,64) f32

    f32x4* wt      = (f32x4*)d_ws;                          // 294912 B
    f32x4* planes4 = (f32x4*)((char*)d_ws + WT_BYTES);      // 4 MB sincos planes

    // prep: 72 weight blocks + 1024 plane blocks
    ring_prep<<<dim3(72 + NPIX / 512), dim3(256), 0, stream>>>(x, w, wt, planes4);

    dim3 grid((H_ / 16) * (W_ / 16), O_ / OC, B_);
    ring_conv<<<grid, dim3(256), 0, stream>>>((const f32x2*)planes4, wt, out);
}